// Round 2
// baseline (62.389 us; speedup 1.0000x reference)
//
#include <hip/hip_runtime.h>

// Problem constants (B=4, N=2048 fixed by the reference setup)
#define BB 4
#define NN 2048
#define TS 128                                  // square row-tile size
#define T_TILES (NN / TS)                       // 16 tiles per batch
#define NPAIRS (T_TILES * (T_TILES + 1) / 2)    // 136 unordered tile pairs (incl. diag)
#define MQ 4                                    // m-quarters per tile pair
#define MSTEP (TS / MQ)                         // 32 m-points per job
#define JOBS_PER_B (NPAIRS * MQ)                // 544
#define NJOBS (JOBS_PER_B * BB)                 // 2176 single-wave jobs
#define BLK 64                                  // one wave per block
#define ROWS 2                                  // n-rows per lane (n-tile = 128)
#define INV_TOTAL (1.0f / ((float)BB * (float)NN * (float)NN))

__device__ __forceinline__ void quat_to_R(float qw, float qx, float qy, float qz, float* R) {
    R[0] = 1.f - 2.f * (qy * qy + qz * qz);
    R[1] = 2.f * (qx * qy - qz * qw);
    R[2] = 2.f * (qx * qz + qy * qw);
    R[3] = 2.f * (qx * qy + qz * qw);
    R[4] = 1.f - 2.f * (qx * qx + qz * qz);
    R[5] = 2.f * (qy * qz - qx * qw);
    R[6] = 2.f * (qx * qz - qy * qw);
    R[7] = 2.f * (qy * qz + qx * qw);
    R[8] = 1.f - 2.f * (qx * qx + qy * qy);
}

// Symmetric-pair kernel: computes lower triangle (m < n) with weight 2.
// Tile pair (ti >= tj): n-side = tile ti (in registers), m-side = tile tj
// quarter (in LDS, 5xfloat4 per point, broadcast reads).
template <bool ATOMIC>
__global__ __launch_bounds__(BLK) void pair_kernel(
    const float* __restrict__ xyz, const float* __restrict__ scales,
    const float* __restrict__ rot, const float* __restrict__ vel,
    float* __restrict__ partials, unsigned int* __restrict__ counter,
    float* __restrict__ outp)
{
    __shared__ float4 sm[MSTEP][5];

    const int lane = threadIdx.x;
    const int jid  = blockIdx.x;
    const int b    = jid / JOBS_PER_B;
    const int rem  = jid % JOBS_PER_B;
    const int p    = rem >> 2;    // triangular pair index
    const int mq   = rem & 3;     // m-quarter

    // decode p -> (ti >= tj), triangular
    int ti = (int)((sqrtf(8.f * (float)p + 1.f) - 1.f) * 0.5f);
    while ((ti + 1) * (ti + 2) / 2 <= p) ++ti;
    while (ti * (ti + 1) / 2 > p) --ti;
    const int tj = p - ti * (ti + 1) / 2;

    const int n_base = ti * TS;
    const int m_base = tj * TS + mq * MSTEP;

    // ---- stage m-quarter into LDS (lanes 0..31, one point each) ----
    if (lane < MSTEP) {
        const int m = m_base + lane;
        const size_t i3 = ((size_t)b * NN + m) * 3;
        const size_t i4 = ((size_t)b * NN + m) * 4;
        const float4 q = *reinterpret_cast<const float4*>(rot + i4);
        float R[9];
        quat_to_R(q.x, q.y, q.z, q.w, R);
        sm[lane][0] = make_float4(xyz[i3], xyz[i3 + 1], xyz[i3 + 2], scales[i3]);
        sm[lane][1] = make_float4(scales[i3 + 1], scales[i3 + 2], vel[i3], vel[i3 + 1]);
        sm[lane][2] = make_float4(vel[i3 + 2], R[0], R[1], R[2]);
        sm[lane][3] = make_float4(R[3], R[4], R[5], R[6]);
        sm[lane][4] = make_float4(R[7], R[8], 0.f, 0.f);
    }

    // ---- n-side rows in registers ----
    float px[ROWS], py[ROWS], pz[ROWS];
    float sx[ROWS], sy[ROWS], sz[ROWS];
    float vx[ROWS], vy[ROWS], vz[ROWS];
    float Rn[ROWS][9];
    int   nidx[ROWS];
    #pragma unroll
    for (int r = 0; r < ROWS; ++r) {
        const int n = n_base + r * BLK + lane;
        nidx[r] = n;
        const size_t i3 = ((size_t)b * NN + n) * 3;
        const size_t i4 = ((size_t)b * NN + n) * 4;
        px[r] = xyz[i3]; py[r] = xyz[i3 + 1]; pz[r] = xyz[i3 + 2];
        sx[r] = scales[i3]; sy[r] = scales[i3 + 1]; sz[r] = scales[i3 + 2];
        vx[r] = vel[i3]; vy[r] = vel[i3 + 1]; vz[r] = vel[i3 + 2];
        const float4 q = *reinterpret_cast<const float4*>(rot + i4);
        quat_to_R(q.x, q.y, q.z, q.w, Rn[r]);
    }

    __syncthreads();

    float acc = 0.f;
    #pragma unroll 4
    for (int j = 0; j < MSTEP; ++j) {
        const int m = m_base + j;                 // uniform
        const float4 c0 = sm[j][0];
        const float4 c1 = sm[j][1];
        const float4 c2 = sm[j][2];
        const float4 c3 = sm[j][3];
        const float4 c4 = sm[j][4];
        const float mx = c0.x, my = c0.y, mz = c0.z;
        const float msx = c0.w, msy = c1.x, msz = c1.y;
        const float mvx = c1.z, mvy = c1.w, mvz = c2.x;
        const float Rm0 = c2.y, Rm1 = c2.z, Rm2 = c2.w;
        const float Rm3 = c3.x, Rm4 = c3.y, Rm5 = c3.z;
        const float Rm6 = c3.w, Rm7 = c4.x, Rm8 = c4.y;
        #pragma unroll
        for (int r = 0; r < ROWS; ++r) {
            const float dx = px[r] - mx, dy = py[r] - my, dz = pz[r] - mz;
            const float d2 = fmaf(dx, dx, fmaf(dy, dy, fmaf(dz, dz, 1e-8f)));
            const float rinv = __builtin_amdgcn_rsqf(d2);
            // r_dir(n,m): (diff^T R_n) scaled by s_m  (dist factored via rinv)
            const float a0 = fmaf(dx, Rn[r][0], fmaf(dy, Rn[r][3], dz * Rn[r][6])) * msx;
            const float a1 = fmaf(dx, Rn[r][1], fmaf(dy, Rn[r][4], dz * Rn[r][7])) * msy;
            const float a2 = fmaf(dx, Rn[r][2], fmaf(dy, Rn[r][5], dz * Rn[r][8])) * msz;
            const float qa = __builtin_amdgcn_sqrtf(fmaf(a0, a0, fmaf(a1, a1, a2 * a2)));
            // r_dir(m,n): (diff^T R_m) scaled by s_n  (sign dies in the square)
            const float b0 = fmaf(dx, Rm0, fmaf(dy, Rm3, dz * Rm6)) * sx[r];
            const float b1 = fmaf(dx, Rm1, fmaf(dy, Rm4, dz * Rm7)) * sy[r];
            const float b2 = fmaf(dx, Rm2, fmaf(dy, Rm5, dz * Rm8)) * sz[r];
            const float qb = __builtin_amdgcn_sqrtf(fmaf(b0, b0, fmaf(b1, b1, b2 * b2)));
            // overlap = rinv * relu(qa + qb - d2)
            const float w  = fmaxf(qa + qb - d2, 0.f);
            const float ov = w * rinv;
            const float rc = __builtin_amdgcn_rcpf(fmaf(0.1f, ov, 1.f));
            // v_approach = (v_n - v_m).diff * rinv ; ramp = relu(-v_approach)
            const float vdot = fmaf(vx[r] - mvx, dx, fmaf(vy[r] - mvy, dy, (vz[r] - mvz) * dz));
            const float ramp = fmaxf(-vdot * rinv, 0.f);
            // t = spec + 0.1*ov*ramp = ov * (ov*rc + 0.1*ramp)
            const float t = ov * fmaf(ov, rc, 0.1f * ramp);
            // weight: 2 for m<n (off-diag tiles have all m<n; diag tiles predicate)
            const float wgt = (m < nidx[r]) ? 2.f : 0.f;
            acc = fmaf(wgt, t, acc);
        }
    }

    // ---- wave reduction (single-wave block) ----
    #pragma unroll
    for (int off = 32; off > 0; off >>= 1)
        acc += __shfl_down(acc, off, 64);

    if (ATOMIC) {
        if (lane == 0) atomicAdd(outp, acc * INV_TOTAL);
        return;
    }

    int last = 0;
    if (lane == 0) {
        partials[jid] = acc;
        __threadfence();                               // release (agent scope, wbl2)
        const unsigned int done = atomicAdd(counter, 1u);
        last = (done == (unsigned int)(NJOBS - 1));
    }
    last = __shfl(last, 0, 64);
    if (last) {
        __threadfence();                               // acquire (invalidate caches)
        const float4* p4 = reinterpret_cast<const float4*>(partials);
        float s = 0.f;
        for (int i = lane; i < NJOBS / 4; i += BLK) {
            const float4 v = p4[i];
            s += v.x + v.y + v.z + v.w;
        }
        #pragma unroll
        for (int off = 32; off > 0; off >>= 1)
            s += __shfl_down(s, off, 64);
        if (lane == 0) outp[0] = s * INV_TOTAL;
    }
}

extern "C" void kernel_launch(void* const* d_in, const int* in_sizes, int n_in,
                              void* d_out, int out_size, void* d_ws, size_t ws_size,
                              hipStream_t stream)
{
    const float* xyz    = (const float*)d_in[0];
    const float* scales = (const float*)d_in[1];
    const float* rot    = (const float*)d_in[2];
    const float* vel    = (const float*)d_in[3];
    float* out = (float*)d_out;

    if (ws_size >= 256 + NJOBS * sizeof(float)) {
        unsigned int* counter = (unsigned int*)d_ws;
        float* partials = (float*)((char*)d_ws + 256);
        hipMemsetAsync(counter, 0, sizeof(unsigned int), stream);   // graph-safe
        pair_kernel<false><<<NJOBS, BLK, 0, stream>>>(xyz, scales, rot, vel,
                                                      partials, counter, out);
    } else {
        hipMemsetAsync(d_out, 0, sizeof(float), stream);
        pair_kernel<true><<<NJOBS, BLK, 0, stream>>>(xyz, scales, rot, vel,
                                                     nullptr, nullptr, out);
    }
}

// Round 3
// 35.135 us; speedup vs baseline: 1.7757x; 1.7757x over previous
//
#include <hip/hip_runtime.h>

// Problem constants (B=4, N=2048 fixed by the reference setup)
#define BB 4
#define NN 2048
#define TS 128                                  // square tile size
#define T_TILES (NN / TS)                       // 16 tiles per batch
#define NPAIRS (T_TILES * (T_TILES + 1) / 2)    // 136 unordered tile pairs (incl. diag)
#define MSPLIT 2                                // m-halves per tile pair (across blocks)
#define MH (TS / MSPLIT)                        // 64 m-points staged per block
#define MT (MH / 2)                             // 32 m-points per thread (msub splits MH)
#define JOBS_PER_B (NPAIRS * MSPLIT)            // 272
#define NJOBS (JOBS_PER_B * BB)                 // 1088 blocks
#define BLK 256                                 // 4 waves per block
// every surviving (m<n) pair carries weight 2 -> fold into final scale
#define SCALE (2.0f / ((float)BB * (float)NN * (float)NN))

__device__ __forceinline__ void quat_to_R(float qw, float qx, float qy, float qz, float* R) {
    R[0] = 1.f - 2.f * (qy * qy + qz * qz);
    R[1] = 2.f * (qx * qy - qz * qw);
    R[2] = 2.f * (qx * qz + qy * qw);
    R[3] = 2.f * (qx * qy + qz * qw);
    R[4] = 1.f - 2.f * (qx * qx + qz * qz);
    R[5] = 2.f * (qy * qz - qx * qw);
    R[6] = 2.f * (qx * qz - qy * qw);
    R[7] = 2.f * (qy * qz + qx * qw);
    R[8] = 1.f - 2.f * (qx * qx + qy * qy);
}

// Lower-triangle (m < n) pair sum, weight 2 folded into SCALE.
// Block: one (tile-pair, m-half, batch). 256 threads: row = tid&127 (n-side,
// in registers), msub = tid>>7 picks 32 of the 64 staged m-points.
template <bool ATOMIC>
__global__ __launch_bounds__(BLK) void pair_kernel(
    const float* __restrict__ xyz, const float* __restrict__ scales,
    const float* __restrict__ rot, const float* __restrict__ vel,
    float* __restrict__ partials, unsigned int* __restrict__ counter,
    float* __restrict__ outp)
{
    __shared__ float4 sm[MH][5];
    __shared__ float wsum[BLK / 64];
    __shared__ int lastflag;

    const int tid = threadIdx.x;
    const int jid = blockIdx.x;
    const int b   = jid / JOBS_PER_B;
    const int rem = jid % JOBS_PER_B;
    const int p   = rem >> 1;      // triangular tile-pair index
    const int mh  = rem & 1;       // m-half

    // decode p -> (ti >= tj)
    int ti = (int)((sqrtf(8.f * (float)p + 1.f) - 1.f) * 0.5f);
    while ((ti + 1) * (ti + 2) / 2 <= p) ++ti;
    while (ti * (ti + 1) / 2 > p) --ti;
    const int tj = p - ti * (ti + 1) / 2;
    const bool diag = (ti == tj);

    const int row   = tid & (TS - 1);
    const int msub  = tid >> 7;
    const int n     = ti * TS + row;
    const int m_blk = tj * TS + mh * MH;

    // ---- stage m-half into LDS (first 64 threads, one point each) ----
    if (tid < MH) {
        const int m = m_blk + tid;
        const size_t i3 = ((size_t)b * NN + m) * 3;
        const size_t i4 = ((size_t)b * NN + m) * 4;
        const float4 q = *reinterpret_cast<const float4*>(rot + i4);
        float R[9];
        quat_to_R(q.x, q.y, q.z, q.w, R);
        sm[tid][0] = make_float4(xyz[i3], xyz[i3 + 1], xyz[i3 + 2], scales[i3]);
        sm[tid][1] = make_float4(scales[i3 + 1], scales[i3 + 2], vel[i3], vel[i3 + 1]);
        sm[tid][2] = make_float4(vel[i3 + 2], R[0], R[1], R[2]);
        sm[tid][3] = make_float4(R[3], R[4], R[5], R[6]);
        sm[tid][4] = make_float4(R[7], R[8], 0.f, 0.f);
    }

    // ---- own n-row in registers ----
    const size_t i3 = ((size_t)b * NN + n) * 3;
    const size_t i4 = ((size_t)b * NN + n) * 4;
    const float px = xyz[i3], py = xyz[i3 + 1], pz = xyz[i3 + 2];
    const float sx = scales[i3], sy = scales[i3 + 1], sz = scales[i3 + 2];
    const float vx = vel[i3], vy = vel[i3 + 1], vz = vel[i3 + 2];
    const float4 qn = *reinterpret_cast<const float4*>(rot + i4);
    float Rn[9];
    quat_to_R(qn.x, qn.y, qn.z, qn.w, Rn);

    __syncthreads();

    float acc = 0.f;
    const int jbase = msub * MT;

    auto inner = [&](bool isDiag) {
        #pragma unroll 4
        for (int jj = 0; jj < MT; ++jj) {
            const int j = jbase + jj;
            const float4 c0 = sm[j][0];
            const float4 c1 = sm[j][1];
            const float4 c2 = sm[j][2];
            const float4 c3 = sm[j][3];
            const float4 c4 = sm[j][4];
            const float dx = px - c0.x, dy = py - c0.y, dz = pz - c0.z;
            const float d2 = fmaf(dx, dx, fmaf(dy, dy, fmaf(dz, dz, 1e-8f)));
            const float rinv = __builtin_amdgcn_rsqf(d2);
            // r_dir(n,m): (diff^T R_n) scaled by s_m
            const float a0 = fmaf(dx, Rn[0], fmaf(dy, Rn[3], dz * Rn[6])) * c0.w;
            const float a1 = fmaf(dx, Rn[1], fmaf(dy, Rn[4], dz * Rn[7])) * c1.x;
            const float a2 = fmaf(dx, Rn[2], fmaf(dy, Rn[5], dz * Rn[8])) * c1.y;
            const float qa = __builtin_amdgcn_sqrtf(fmaf(a0, a0, fmaf(a1, a1, a2 * a2)));
            // r_dir(m,n): (diff^T R_m) scaled by s_n (sign dies in the square)
            const float b0 = fmaf(dx, c2.y, fmaf(dy, c3.x, dz * c3.w)) * sx;
            const float b1 = fmaf(dx, c2.z, fmaf(dy, c3.y, dz * c4.x)) * sy;
            const float b2 = fmaf(dx, c2.w, fmaf(dy, c3.z, dz * c4.y)) * sz;
            const float qb = __builtin_amdgcn_sqrtf(fmaf(b0, b0, fmaf(b1, b1, b2 * b2)));
            // overlap = rinv * relu(qa + qb - d2)
            const float w  = fmaxf(qa + qb - d2, 0.f);
            const float ov = w * rinv;
            const float rc = __builtin_amdgcn_rcpf(fmaf(0.1f, ov, 1.f));
            // v_approach = (v_n - v_m).diff * rinv ; ramp = relu(-v_approach)
            const float vdot = fmaf(vx - c1.z, dx, fmaf(vy - c1.w, dy, (vz - c2.x) * dz));
            const float ramp = fmaxf(-vdot * rinv, 0.f);
            // t = spec + 0.1*ov*ramp = ov * (ov*rc + 0.1*ramp)
            float t = ov * fmaf(ov, rc, 0.1f * ramp);
            if (isDiag && !(m_blk + j < n)) t = 0.f;   // diag tiles: keep m<n only
            acc += t;
        }
    };
    if (diag) inner(true); else inner(false);

    // ---- block reduction (4 waves) ----
    #pragma unroll
    for (int off = 32; off > 0; off >>= 1)
        acc += __shfl_down(acc, off, 64);
    if ((tid & 63) == 0) wsum[tid >> 6] = acc;
    __syncthreads();

    if (ATOMIC) {
        if (tid == 0) atomicAdd(outp, (wsum[0] + wsum[1] + wsum[2] + wsum[3]) * SCALE);
        return;
    }

    if (tid == 0) {
        const float tot = wsum[0] + wsum[1] + wsum[2] + wsum[3];
        partials[jid] = tot;
        __threadfence();                               // release
        const unsigned int done = atomicAdd(counter, 1u);
        lastflag = (done == (unsigned int)(NJOBS - 1));
    }
    __syncthreads();

    if (lastflag && tid < 64) {
        __threadfence();                               // acquire
        const float4* p4 = reinterpret_cast<const float4*>(partials);
        float s = 0.f;
        #pragma unroll
        for (int i = tid; i < NJOBS / 4; i += 64) {
            const float4 v = p4[i];
            s += v.x + v.y + v.z + v.w;
        }
        #pragma unroll
        for (int off = 32; off > 0; off >>= 1)
            s += __shfl_down(s, off, 64);
        if (tid == 0) outp[0] = s * SCALE;
    }
}

extern "C" void kernel_launch(void* const* d_in, const int* in_sizes, int n_in,
                              void* d_out, int out_size, void* d_ws, size_t ws_size,
                              hipStream_t stream)
{
    const float* xyz    = (const float*)d_in[0];
    const float* scales = (const float*)d_in[1];
    const float* rot    = (const float*)d_in[2];
    const float* vel    = (const float*)d_in[3];
    float* out = (float*)d_out;

    if (ws_size >= 256 + NJOBS * sizeof(float)) {
        unsigned int* counter = (unsigned int*)d_ws;
        float* partials = (float*)((char*)d_ws + 256);
        hipMemsetAsync(counter, 0, sizeof(unsigned int), stream);   // graph-safe
        pair_kernel<false><<<NJOBS, BLK, 0, stream>>>(xyz, scales, rot, vel,
                                                      partials, counter, out);
    } else {
        hipMemsetAsync(d_out, 0, sizeof(float), stream);
        pair_kernel<true><<<NJOBS, BLK, 0, stream>>>(xyz, scales, rot, vel,
                                                     nullptr, nullptr, out);
    }
}